// Round 11
// baseline (691.713 us; speedup 1.0000x reference)
//
#include <hip/hip_runtime.h>
#include <hip/hip_bf16.h>
#include <stdint.h>

#define N_BATCH 4096
#define D_DIM   1024
#define M_ROWS  8192                     // 2N
#define TINV    2.0f                     // 1/temperature
// acc = sum q(16 z_r) q(16 z_c) = 256*sim ; exp2(acc * log2(e)/(256 t))
#define EXP_SCALE_Q (2.8853900817779268f / 256.0f)
#define LN2 0.6931471805599453f
#define NB 64                            // 8192/128 tiles per dim
#define NTRI 2080                        // NB*(NB+1)/2 upper-tri tiles
#define NK128 8                          // K steps of 128 (K=1024)
#define UNIT_SCALE 0x7F7F7F7F            // E8M0 127 = x2^0 in every byte

typedef float f32x4  __attribute__((ext_vector_type(4)));
typedef int   int32x8 __attribute__((ext_vector_type(8)));

// ---- kernel 1: fused L2-normalize (fp8 e4m3 Z out, x16 scale) + positives --
__global__ __launch_bounds__(256) void norm_pos_kernel(
    const float* __restrict__ emb_i, const float* __restrict__ emb_j,
    uint8_t* __restrict__ z8, float* __restrict__ pos, float* __restrict__ denom)
{
    int w    = threadIdx.x >> 6;                 // wave 0..3
    int lane = threadIdx.x & 63;
    int row  = blockIdx.x * 4 + w;               // 0..4095 (grid = 1024)
    const float4* Ai = (const float4*)(emb_i + (size_t)row * D_DIM);
    const float4* Bj = (const float4*)(emb_j + (size_t)row * D_DIM);
    float4 a[4], b[4];
    #pragma unroll
    for (int j = 0; j < 4; ++j) {
        a[j] = Ai[lane + 64 * j];
        b[j] = Bj[lane + 64 * j];
    }
    float ssa = 0.f, ssb = 0.f, dot = 0.f;
    #pragma unroll
    for (int j = 0; j < 4; ++j) {
        ssa += a[j].x*a[j].x + a[j].y*a[j].y + a[j].z*a[j].z + a[j].w*a[j].w;
        ssb += b[j].x*b[j].x + b[j].y*b[j].y + b[j].z*b[j].z + b[j].w*b[j].w;
        dot += a[j].x*b[j].x + a[j].y*b[j].y + a[j].z*b[j].z + a[j].w*b[j].w;
    }
    #pragma unroll
    for (int m = 1; m < 64; m <<= 1) {
        ssa += __shfl_xor(ssa, m, 64);
        ssb += __shfl_xor(ssb, m, 64);
        dot += __shfl_xor(dot, m, 64);
    }
    float na = fmaxf(sqrtf(ssa), 1e-12f);
    float nb = fmaxf(sqrtf(ssb), 1e-12f);
    float sa = 16.0f / na, sb = 16.0f / nb;
    uint32_t* zr = (uint32_t*)(z8 + (size_t)row * D_DIM);
    uint32_t* zc = (uint32_t*)(z8 + (size_t)(row + N_BATCH) * D_DIM);
    #pragma unroll
    for (int j = 0; j < 4; ++j) {
        int ra = 0, rb = 0;
        ra = __builtin_amdgcn_cvt_pk_fp8_f32(a[j].x * sa, a[j].y * sa, ra, false);
        ra = __builtin_amdgcn_cvt_pk_fp8_f32(a[j].z * sa, a[j].w * sa, ra, true);
        rb = __builtin_amdgcn_cvt_pk_fp8_f32(b[j].x * sb, b[j].y * sb, rb, false);
        rb = __builtin_amdgcn_cvt_pk_fp8_f32(b[j].z * sb, b[j].w * sb, rb, true);
        zr[lane + 64 * j] = (uint32_t)ra;
        zc[lane + 64 * j] = (uint32_t)rb;
    }
    if (lane == 0) {
        pos[row] = dot / ((na * nb) / 256.0f) / 256.0f;  // == dot/(na*nb)
        denom[row] = 0.0f;
        denom[row + N_BATCH] = 0.0f;
    }
}

// ---- kernel 2: fused sim = Z Z^T -> exp -> masked row/col sums -----------
// MX-scale fp8 K=128 port of the proven skeleton (ladder step 3-mx, m148:
// m97-structure + MX fp8 K=128 = 1628 TF on this chip):
//  - mfma_scale_f32_16x16x128_f8f6f4 with UNIT scales (E8M0 0x7F = x1):
//    numerically identical to plain fp8 dot w/ fp32 accum, 2x MFMA rate,
//    K=128 per instruction -> 8 barrier-steps instead of 16.
//  - single 32 KiB buffer (3 blk/CU preserved) + T14 reg double-buffer:
//    issue step j+1's 8 global loads at top; frag-reads+MFMA on step j
//    cover them; barrier (reads done) -> vmcnt(0) -> 8 ds_write_b128 ->
//    lgkmcnt(0) -> barrier.
//  - LDS layout [row 0..127][128B] with 16B-slot rotation slot'=(slot+row)&7
//    (reg-staging = free layout): EVERY read & write instruction's 8-lane
//    phases cover all 32 banks -> conflict-free by construction.
//  - frag: lane (l15=row, quad) holds k in [quad*32, quad*32+32) -- the
//    verified fp8 K=32 pattern (k = quad*8) scaled x4; read as 2x b128 at
//    slots quad*2, quad*2+1 (rotated).
__global__ __launch_bounds__(256, 3) void simexp_kernel(
    const uint8_t* __restrict__ Z, float* __restrict__ denom)
{
    // XCD swizzle then decode linear idx -> (by, bx) with bx >= by
    int orig = blockIdx.x;
    int idx  = (orig & 7) * (NTRI / 8) + (orig >> 3);
    int by = (int)((129.0f - sqrtf(16641.0f - 8.0f * (float)idx)) * 0.5f);
    if (by > NB - 1) by = NB - 1;
    if (by < 0) by = 0;
    int off = (by * (129 - by)) >> 1;           // tiles before row `by`
    while (off > idx)                 { --by; off = (by * (129 - by)) >> 1; }
    while (off + (NB - by) <= idx)    { off += NB - by; ++by; }
    int bx = by + (idx - off);

    int tile_m = by * 128, tile_n = bx * 128;

    __shared__ __align__(16) uint8_t shA[128 * 128];   // 16 KiB
    __shared__ __align__(16) uint8_t shB[128 * 128];   // 16 KiB

    int t    = threadIdx.x;
    int lane = t & 63;
    int wv   = t >> 6;
    int wave_m = (wv >> 1) * 64;
    int wave_n = (wv & 1) * 64;
    int quad = lane >> 4;
    int l15  = lane & 15;

    // staging: thread t owns row = t>>1, slots sbase..sbase+3 (sbase = 4*(t&1))
    int srow  = t >> 1;
    int sbase = (t & 1) * 4;
    const uint8_t* gA = Z + (size_t)(tile_m + srow) * D_DIM;
    const uint8_t* gB = Z + (size_t)(tile_n + srow) * D_DIM;
    int woff[4];
    #pragma unroll
    for (int c = 0; c < 4; ++c)
        woff[c] = srow * 128 + (((sbase + c) + srow) & 7) * 16;

    f32x4 acc[4][4] = {};
    union V8 { int4 q[2]; int32x8 v; };
    int4 sa[4], sb[4];

    // prologue: stage K-step 0
    #pragma unroll
    for (int c = 0; c < 4; ++c) {
        sa[c] = *(const int4*)(gA + (sbase + c) * 16);
        sb[c] = *(const int4*)(gB + (sbase + c) * 16);
    }
    asm volatile("s_waitcnt vmcnt(0)" ::: "memory");
    __builtin_amdgcn_sched_barrier(0);
    #pragma unroll
    for (int c = 0; c < 4; ++c) {
        *(int4*)&shA[woff[c]] = sa[c];
        *(int4*)&shB[woff[c]] = sb[c];
    }
    asm volatile("s_waitcnt lgkmcnt(0)" ::: "memory");
    __builtin_amdgcn_sched_barrier(0);
    __builtin_amdgcn_s_barrier();

    for (int j = 0; j < NK128; ++j) {
        bool stg = (j < NK128 - 1);
        if (stg) {                       // issue step j+1 loads EARLY (T14)
            int k0 = (j + 1) * 128;
            #pragma unroll
            for (int c = 0; c < 4; ++c) {
                sa[c] = *(const int4*)(gA + k0 + (sbase + c) * 16);
                sb[c] = *(const int4*)(gB + k0 + (sbase + c) * 16);
            }
        }
        // B fragments (4 x 32B), rotated-slot b128 reads, conflict-free
        V8 bfr[4];
        #pragma unroll
        for (int n = 0; n < 4; ++n) {
            int r = wave_n + n * 16 + l15;
            int base = r * 128;
            bfr[n].q[0] = *(const int4*)&shB[base + ((quad * 2     + r) & 7) * 16];
            bfr[n].q[1] = *(const int4*)&shB[base + ((quad * 2 + 1 + r) & 7) * 16];
        }
        __builtin_amdgcn_s_setprio(1);
        #pragma unroll
        for (int fm = 0; fm < 4; ++fm) {
            V8 af;
            int r = wave_m + fm * 16 + l15;
            int base = r * 128;
            af.q[0] = *(const int4*)&shA[base + ((quad * 2     + r) & 7) * 16];
            af.q[1] = *(const int4*)&shA[base + ((quad * 2 + 1 + r) & 7) * 16];
            #pragma unroll
            for (int n = 0; n < 4; ++n)
                acc[fm][n] = __builtin_amdgcn_mfma_scale_f32_16x16x128_f8f6f4(
                    af.v, bfr[n].v, acc[fm][n], 0, 0,
                    0, UNIT_SCALE, 0, UNIT_SCALE);
        }
        __builtin_amdgcn_s_setprio(0);
        __builtin_amdgcn_s_barrier();    // all waves done READING the buffer
        if (stg) {
            asm volatile("s_waitcnt vmcnt(0)" ::: "memory");
            __builtin_amdgcn_sched_barrier(0);
            #pragma unroll
            for (int c = 0; c < 4; ++c) {
                *(int4*)&shA[woff[c]] = sa[c];
                *(int4*)&shB[woff[c]] = sb[c];
            }
            asm volatile("s_waitcnt lgkmcnt(0)" ::: "memory");
            __builtin_amdgcn_sched_barrier(0);
            __builtin_amdgcn_s_barrier(); // buffer refilled for step j+1
        }
    }

    // epilogue: e = exp2(acc * log2(e)/(256 t)) only where c>r; row/col sums
    int rbase = tile_m + wave_m + quad * 4;
    int cbase = tile_n + wave_n + l15;
    float colacc[4] = {0.f, 0.f, 0.f, 0.f};
    #pragma unroll
    for (int fm = 0; fm < 4; ++fm) {
        #pragma unroll
        for (int r = 0; r < 4; ++r) {
            int rg = rbase + fm * 16 + r;
            float rowacc = 0.f;
            #pragma unroll
            for (int fn = 0; fn < 4; ++fn) {
                int cg = cbase + fn * 16;
                float e = (cg > rg)
                    ? __builtin_amdgcn_exp2f(acc[fm][fn][r] * EXP_SCALE_Q)
                    : 0.f;
                rowacc += e;
                colacc[fn] += e;
            }
            rowacc += __shfl_xor(rowacc, 1, 64);
            rowacc += __shfl_xor(rowacc, 2, 64);
            rowacc += __shfl_xor(rowacc, 4, 64);
            rowacc += __shfl_xor(rowacc, 8, 64);
            if (l15 == 0) atomicAdd(&denom[rg], rowacc);
        }
    }
    #pragma unroll
    for (int fn = 0; fn < 4; ++fn) {
        float s = colacc[fn];
        s += __shfl_xor(s, 16, 64);
        s += __shfl_xor(s, 32, 64);
        if (quad == 0) atomicAdd(&denom[cbase + fn * 16], s);
    }
}

// ---- kernel 3: loss = [sum log(denom) - (2/t) sum pos] / 2N --------------
__global__ __launch_bounds__(1024) void finalize_kernel(
    const float* __restrict__ denom, const float* __restrict__ pos,
    float* __restrict__ out)
{
    float a1 = 0.f, a2 = 0.f;
    for (int r = threadIdx.x; r < M_ROWS; r += 1024)
        a1 += __builtin_amdgcn_logf(denom[r]) * LN2;   // v_log_f32 is log2
    for (int i = threadIdx.x; i < N_BATCH; i += 1024)
        a2 += pos[i];
    #pragma unroll
    for (int m = 1; m < 64; m <<= 1) {
        a1 += __shfl_xor(a1, m, 64);
        a2 += __shfl_xor(a2, m, 64);
    }
    __shared__ float r1[16], r2[16];
    int wv = threadIdx.x >> 6;
    if ((threadIdx.x & 63) == 0) { r1[wv] = a1; r2[wv] = a2; }
    __syncthreads();
    if (threadIdx.x == 0) {
        float s1 = 0.f, s2 = 0.f;
        #pragma unroll
        for (int w = 0; w < 16; ++w) { s1 += r1[w]; s2 += r2[w]; }
        out[0] = (s1 - 2.0f * TINV * s2) / (float)M_ROWS;
    }
}

extern "C" void kernel_launch(void* const* d_in, const int* in_sizes, int n_in,
                              void* d_out, int out_size, void* d_ws, size_t ws_size,
                              hipStream_t stream)
{
    const float* emb_i = (const float*)d_in[0];
    const float* emb_j = (const float*)d_in[1];
    float* out = (float*)d_out;

    char*    ws    = (char*)d_ws;
    uint8_t* z8    = (uint8_t*)ws;                                 // 8 MB
    float*   denom = (float*)(ws + (size_t)M_ROWS * D_DIM);        // 32 KB
    float*   pos   = denom + M_ROWS;                               // 16 KB

    hipLaunchKernelGGL(norm_pos_kernel, dim3(N_BATCH / 4), dim3(256), 0, stream,
                       emb_i, emb_j, z8, pos, denom);
    hipLaunchKernelGGL(simexp_kernel, dim3(NTRI), dim3(256), 0, stream,
                       z8, denom);
    hipLaunchKernelGGL(finalize_kernel, dim3(1), dim3(1024), 0, stream,
                       denom, pos, out);
}

// Round 12
// 195.480 us; speedup vs baseline: 3.5385x; 3.5385x over previous
//
#include <hip/hip_runtime.h>
#include <hip/hip_bf16.h>
#include <stdint.h>

#define N_BATCH 4096
#define D_DIM   1024
#define M_ROWS  8192                     // 2N
#define TINV    2.0f                     // 1/temperature
// acc = sum q(16 z_r) q(16 z_c) = 256*sim ; exp2(acc * log2(e)/(256 t))
#define EXP_SCALE_Q (2.8853900817779268f / 256.0f)
#define LN2 0.6931471805599453f
#define NB 64                            // 8192/128 tiles per dim
#define NTRI 2080                        // NB*(NB+1)/2 upper-tri tiles
#define NK128 8                          // K steps of 128 (K=1024)
#define UNIT_SCALE 0x7F7F7F7F            // E8M0 127 = x2^0 in every byte

typedef float f32x4 __attribute__((ext_vector_type(4)));
typedef int   i32x4 __attribute__((ext_vector_type(4)));
typedef int   i32x8 __attribute__((ext_vector_type(8)));

// ---- kernel 1: fused L2-normalize (fp8 e4m3 Z out, x16 scale) + positives --
__global__ __launch_bounds__(256) void norm_pos_kernel(
    const float* __restrict__ emb_i, const float* __restrict__ emb_j,
    uint8_t* __restrict__ z8, float* __restrict__ pos, float* __restrict__ denom)
{
    int w    = threadIdx.x >> 6;                 // wave 0..3
    int lane = threadIdx.x & 63;
    int row  = blockIdx.x * 4 + w;               // 0..4095 (grid = 1024)
    const float4* Ai = (const float4*)(emb_i + (size_t)row * D_DIM);
    const float4* Bj = (const float4*)(emb_j + (size_t)row * D_DIM);
    float4 a[4], b[4];
    #pragma unroll
    for (int j = 0; j < 4; ++j) {
        a[j] = Ai[lane + 64 * j];
        b[j] = Bj[lane + 64 * j];
    }
    float ssa = 0.f, ssb = 0.f, dot = 0.f;
    #pragma unroll
    for (int j = 0; j < 4; ++j) {
        ssa += a[j].x*a[j].x + a[j].y*a[j].y + a[j].z*a[j].z + a[j].w*a[j].w;
        ssb += b[j].x*b[j].x + b[j].y*b[j].y + b[j].z*b[j].z + b[j].w*b[j].w;
        dot += a[j].x*b[j].x + a[j].y*b[j].y + a[j].z*b[j].z + a[j].w*b[j].w;
    }
    #pragma unroll
    for (int m = 1; m < 64; m <<= 1) {
        ssa += __shfl_xor(ssa, m, 64);
        ssb += __shfl_xor(ssb, m, 64);
        dot += __shfl_xor(dot, m, 64);
    }
    float na = fmaxf(sqrtf(ssa), 1e-12f);
    float nb = fmaxf(sqrtf(ssb), 1e-12f);
    float sa = 16.0f / na, sb = 16.0f / nb;
    uint32_t* zr = (uint32_t*)(z8 + (size_t)row * D_DIM);
    uint32_t* zc = (uint32_t*)(z8 + (size_t)(row + N_BATCH) * D_DIM);
    #pragma unroll
    for (int j = 0; j < 4; ++j) {
        int ra = 0, rb = 0;
        ra = __builtin_amdgcn_cvt_pk_fp8_f32(a[j].x * sa, a[j].y * sa, ra, false);
        ra = __builtin_amdgcn_cvt_pk_fp8_f32(a[j].z * sa, a[j].w * sa, ra, true);
        rb = __builtin_amdgcn_cvt_pk_fp8_f32(b[j].x * sb, b[j].y * sb, rb, false);
        rb = __builtin_amdgcn_cvt_pk_fp8_f32(b[j].z * sb, b[j].w * sb, rb, true);
        zr[lane + 64 * j] = (uint32_t)ra;
        zc[lane + 64 * j] = (uint32_t)rb;
    }
    if (lane == 0) {
        pos[row] = dot / ((na * nb) / 256.0f) / 256.0f;  // == dot/(na*nb)
        denom[row] = 0.0f;
        denom[row + N_BATCH] = 0.0f;
    }
}

// ---- kernel 2: fused sim = Z Z^T -> exp -> masked row/col sums -----------
// MX-scale fp8 K=128 (round-11 structure, HW-verified correct) with the
// scratch-spill bug fixed:
//  - NO union type-pun: all 16B moves use ext_vector i32x4; the v8i32 MFMA
//    operand is built with __builtin_shufflevector (pure register code).
//    Round 11's union{HIP int4 struct, ext_vector} defeated SROA -> alloca
//    -> 1.2 GB/dispatch scratch traffic (WRITE_SIZE counter).
//  - plain __launch_bounds__(256): no min-wave clamp that could force
//    spilling at ~150-170 live VGPRs; allocator lands at 3 waves/SIMD.
// Schedule/layout identical to round 11:
//  - mfma_scale_f32_16x16x128_f8f6f4, UNIT E8M0 scales (x1) == plain fp8
//    dot with fp32 accum; 8 barrier-steps; single 32 KiB buffer; T14 reg
//    double-buffer (issue j+1 loads at top, write after read-barrier).
//  - LDS [row][128B], 16B-slot rotation slot'=(slot+row)&7: every read and
//    write instruction's 8-lane phases cover all 32 banks.
__global__ __launch_bounds__(256) void simexp_kernel(
    const uint8_t* __restrict__ Z, float* __restrict__ denom)
{
    // XCD swizzle then decode linear idx -> (by, bx) with bx >= by
    int orig = blockIdx.x;
    int idx  = (orig & 7) * (NTRI / 8) + (orig >> 3);
    int by = (int)((129.0f - sqrtf(16641.0f - 8.0f * (float)idx)) * 0.5f);
    if (by > NB - 1) by = NB - 1;
    if (by < 0) by = 0;
    int off = (by * (129 - by)) >> 1;           // tiles before row `by`
    while (off > idx)                 { --by; off = (by * (129 - by)) >> 1; }
    while (off + (NB - by) <= idx)    { off += NB - by; ++by; }
    int bx = by + (idx - off);

    int tile_m = by * 128, tile_n = bx * 128;

    __shared__ __align__(16) uint8_t shA[128 * 128];   // 16 KiB
    __shared__ __align__(16) uint8_t shB[128 * 128];   // 16 KiB

    int t    = threadIdx.x;
    int lane = t & 63;
    int wv   = t >> 6;
    int wave_m = (wv >> 1) * 64;
    int wave_n = (wv & 1) * 64;
    int quad = lane >> 4;
    int l15  = lane & 15;

    // staging: thread t owns row = t>>1, slots sbase..sbase+3 (sbase = 4*(t&1))
    int srow  = t >> 1;
    int sbase = (t & 1) * 4;
    const uint8_t* gA = Z + (size_t)(tile_m + srow) * D_DIM;
    const uint8_t* gB = Z + (size_t)(tile_n + srow) * D_DIM;
    int woff[4];
    #pragma unroll
    for (int c = 0; c < 4; ++c)
        woff[c] = srow * 128 + (((sbase + c) + srow) & 7) * 16;

    f32x4 acc[4][4] = {};
    i32x4 sa[4], sb[4];

    // prologue: stage K-step 0
    #pragma unroll
    for (int c = 0; c < 4; ++c) {
        sa[c] = *(const i32x4*)(gA + (sbase + c) * 16);
        sb[c] = *(const i32x4*)(gB + (sbase + c) * 16);
    }
    asm volatile("s_waitcnt vmcnt(0)" ::: "memory");
    __builtin_amdgcn_sched_barrier(0);
    #pragma unroll
    for (int c = 0; c < 4; ++c) {
        *(i32x4*)&shA[woff[c]] = sa[c];
        *(i32x4*)&shB[woff[c]] = sb[c];
    }
    asm volatile("s_waitcnt lgkmcnt(0)" ::: "memory");
    __builtin_amdgcn_sched_barrier(0);
    __builtin_amdgcn_s_barrier();

    for (int j = 0; j < NK128; ++j) {
        bool stg = (j < NK128 - 1);
        if (stg) {                       // issue step j+1 loads EARLY (T14)
            int k0 = (j + 1) * 128;
            #pragma unroll
            for (int c = 0; c < 4; ++c) {
                sa[c] = *(const i32x4*)(gA + k0 + (sbase + c) * 16);
                sb[c] = *(const i32x4*)(gB + k0 + (sbase + c) * 16);
            }
        }
        // B fragments (4 x 32B), rotated-slot b128 reads, conflict-free
        i32x8 bfr[4];
        #pragma unroll
        for (int n = 0; n < 4; ++n) {
            int r = wave_n + n * 16 + l15;
            int base = r * 128;
            i32x4 q0 = *(const i32x4*)&shB[base + ((quad * 2     + r) & 7) * 16];
            i32x4 q1 = *(const i32x4*)&shB[base + ((quad * 2 + 1 + r) & 7) * 16];
            bfr[n] = __builtin_shufflevector(q0, q1, 0, 1, 2, 3, 4, 5, 6, 7);
        }
        __builtin_amdgcn_s_setprio(1);
        #pragma unroll
        for (int fm = 0; fm < 4; ++fm) {
            int r = wave_m + fm * 16 + l15;
            int base = r * 128;
            i32x4 q0 = *(const i32x4*)&shA[base + ((quad * 2     + r) & 7) * 16];
            i32x4 q1 = *(const i32x4*)&shA[base + ((quad * 2 + 1 + r) & 7) * 16];
            i32x8 a8 = __builtin_shufflevector(q0, q1, 0, 1, 2, 3, 4, 5, 6, 7);
            #pragma unroll
            for (int n = 0; n < 4; ++n)
                acc[fm][n] = __builtin_amdgcn_mfma_scale_f32_16x16x128_f8f6f4(
                    a8, bfr[n], acc[fm][n], 0, 0,
                    0, UNIT_SCALE, 0, UNIT_SCALE);
        }
        __builtin_amdgcn_s_setprio(0);
        __builtin_amdgcn_s_barrier();    // all waves done READING the buffer
        if (stg) {
            asm volatile("s_waitcnt vmcnt(0)" ::: "memory");
            __builtin_amdgcn_sched_barrier(0);
            #pragma unroll
            for (int c = 0; c < 4; ++c) {
                *(i32x4*)&shA[woff[c]] = sa[c];
                *(i32x4*)&shB[woff[c]] = sb[c];
            }
            asm volatile("s_waitcnt lgkmcnt(0)" ::: "memory");
            __builtin_amdgcn_sched_barrier(0);
            __builtin_amdgcn_s_barrier(); // buffer refilled for step j+1
        }
    }

    // epilogue: e = exp2(acc * log2(e)/(256 t)) only where c>r; row/col sums
    int rbase = tile_m + wave_m + quad * 4;
    int cbase = tile_n + wave_n + l15;
    float colacc[4] = {0.f, 0.f, 0.f, 0.f};
    #pragma unroll
    for (int fm = 0; fm < 4; ++fm) {
        #pragma unroll
        for (int r = 0; r < 4; ++r) {
            int rg = rbase + fm * 16 + r;
            float rowacc = 0.f;
            #pragma unroll
            for (int fn = 0; fn < 4; ++fn) {
                int cg = cbase + fn * 16;
                float e = (cg > rg)
                    ? __builtin_amdgcn_exp2f(acc[fm][fn][r] * EXP_SCALE_Q)
                    : 0.f;
                rowacc += e;
                colacc[fn] += e;
            }
            rowacc += __shfl_xor(rowacc, 1, 64);
            rowacc += __shfl_xor(rowacc, 2, 64);
            rowacc += __shfl_xor(rowacc, 4, 64);
            rowacc += __shfl_xor(rowacc, 8, 64);
            if (l15 == 0) atomicAdd(&denom[rg], rowacc);
        }
    }
    #pragma unroll
    for (int fn = 0; fn < 4; ++fn) {
        float s = colacc[fn];
        s += __shfl_xor(s, 16, 64);
        s += __shfl_xor(s, 32, 64);
        if (quad == 0) atomicAdd(&denom[cbase + fn * 16], s);
    }
}

// ---- kernel 3: loss = [sum log(denom) - (2/t) sum pos] / 2N --------------
__global__ __launch_bounds__(1024) void finalize_kernel(
    const float* __restrict__ denom, const float* __restrict__ pos,
    float* __restrict__ out)
{
    float a1 = 0.f, a2 = 0.f;
    for (int r = threadIdx.x; r < M_ROWS; r += 1024)
        a1 += __builtin_amdgcn_logf(denom[r]) * LN2;   // v_log_f32 is log2
    for (int i = threadIdx.x; i < N_BATCH; i += 1024)
        a2 += pos[i];
    #pragma unroll
    for (int m = 1; m < 64; m <<= 1) {
        a1 += __shfl_xor(a1, m, 64);
        a2 += __shfl_xor(a2, m, 64);
    }
    __shared__ float r1[16], r2[16];
    int wv = threadIdx.x >> 6;
    if ((threadIdx.x & 63) == 0) { r1[wv] = a1; r2[wv] = a2; }
    __syncthreads();
    if (threadIdx.x == 0) {
        float s1 = 0.f, s2 = 0.f;
        #pragma unroll
        for (int w = 0; w < 16; ++w) { s1 += r1[w]; s2 += r2[w]; }
        out[0] = (s1 - 2.0f * TINV * s2) / (float)M_ROWS;
    }
}

extern "C" void kernel_launch(void* const* d_in, const int* in_sizes, int n_in,
                              void* d_out, int out_size, void* d_ws, size_t ws_size,
                              hipStream_t stream)
{
    const float* emb_i = (const float*)d_in[0];
    const float* emb_j = (const float*)d_in[1];
    float* out = (float*)d_out;

    char*    ws    = (char*)d_ws;
    uint8_t* z8    = (uint8_t*)ws;                                 // 8 MB
    float*   denom = (float*)(ws + (size_t)M_ROWS * D_DIM);        // 32 KB
    float*   pos   = denom + M_ROWS;                               // 16 KB

    hipLaunchKernelGGL(norm_pos_kernel, dim3(N_BATCH / 4), dim3(256), 0, stream,
                       emb_i, emb_j, z8, pos, denom);
    hipLaunchKernelGGL(simexp_kernel, dim3(NTRI), dim3(256), 0, stream,
                       z8, denom);
    hipLaunchKernelGGL(finalize_kernel, dim3(1), dim3(1024), 0, stream,
                       denom, pos, out);
}